// Round 5
// baseline (371.218 us; speedup 1.0000x reference)
//
#include <hip/hip_runtime.h>
#include <hip/hip_bf16.h>

typedef short bf16x8 __attribute__((ext_vector_type(8)));
typedef unsigned short u16x8 __attribute__((ext_vector_type(8)));
typedef float f32x4 __attribute__((ext_vector_type(4)));

#define CCH 512
#define NPIX 4096
#define NB 4

__device__ inline unsigned short f2bf(float f) {
  union { __hip_bfloat16 h; unsigned short u; } cv;
  cv.h = __float2bfloat16(f);
  return cv.u;
}
__device__ inline float bf2f(unsigned short u) {
  union { float f; unsigned int i; } c;
  c.i = ((unsigned int)u) << 16;
  return c.f;
}

#define GLD16(gp, lp) __builtin_amdgcn_global_load_lds( \
    (const __attribute__((address_space(1))) unsigned int*)(gp), \
    (__attribute__((address_space(3))) unsigned int*)(lp), 16, 0, 0)

// ---------------- weight fp32 -> bf16 cast ----------------
__global__ __launch_bounds__(256) void cast_weights_k(
    const float* __restrict__ w0, const float* __restrict__ w1,
    const float* __restrict__ w2, const float* __restrict__ w3,
    unsigned short* __restrict__ out) {
  int z = blockIdx.y;
  const float* src = (z == 0) ? w0 : (z == 1) ? w1 : (z == 2) ? w2 : w3;
  long i = (long)blockIdx.x * 256 + threadIdx.x;
  out[(long)z * CCH * CCH + i] = f2bf(src[i]);
}

// ---------------- concat bq,bk -> bqk[1024] ----------------
__global__ __launch_bounds__(256) void bias_concat_k(
    const float* __restrict__ bq, const float* __restrict__ bk,
    float* __restrict__ bqk) {
  int i = blockIdx.x * 256 + threadIdx.x;
  bqk[i] = (i < CCH) ? bq[i] : bk[i - CCH];
}

// ---------------- zero the softmax row-sum accumulator ----------------
__global__ __launch_bounds__(256) void zero_l_k(float* __restrict__ lsum) {
  int i = (blockIdx.x * 256 + threadIdx.x) * 4;
  *(float4*)(lsum + i) = make_float4(0.f, 0.f, 0.f, 0.f);
}

// ---------------- instance-norm stats: one block per (b,c) plane ----------------
__global__ __launch_bounds__(256) void stats_k(const float* __restrict__ x,
                                               float* __restrict__ stats) {
  long plane = blockIdx.x;
  const float4* p = (const float4*)(x + plane * NPIX);
  int t = threadIdx.x;
  float s = 0.f, q = 0.f;
  for (int c = 0; c < 4; c++) {
    float4 v = p[c * 256 + t];
    s += v.x + v.y + v.z + v.w;
    q += v.x * v.x + v.y * v.y + v.z * v.z + v.w * v.w;
  }
  for (int off = 32; off; off >>= 1) { s += __shfl_xor(s, off); q += __shfl_xor(q, off); }
  __shared__ float rs[4], rq[4];
  int w = t >> 6;
  if ((t & 63) == 0) { rs[w] = s; rq[w] = q; }
  __syncthreads();
  if (t == 0) {
    s = rs[0] + rs[1] + rs[2] + rs[3];
    q = rq[0] + rq[1] + rq[2] + rq[3];
    float mu = s * (1.f / NPIX);
    float var = q * (1.f / NPIX) - mu * mu;
    stats[2 * plane] = mu;
    stats[2 * plane + 1] = rsqrtf(var + 1e-5f);
  }
}

// ---------------- normalize + transpose: x[b][c][i] -> hnT[b][i][c] bf16 ----------------
__global__ __launch_bounds__(256) void norm_t_k(const float* __restrict__ x,
                                                const float* __restrict__ stats,
                                                unsigned short* __restrict__ hnT) {
  int b = blockIdx.z;
  int c0 = blockIdx.y * 32, i0 = blockIdx.x * 32;
  __shared__ float tile[32][33];
  int t = threadIdx.x;
  int il = t & 31, cl = t >> 5;  // cl in 0..7
  for (int r = 0; r < 4; r++) {
    int c = c0 + cl + r * 8;
    long pl = (long)b * CCH + c;
    float mu = stats[2 * pl], rsg = stats[2 * pl + 1];
    tile[cl + r * 8][il] = (x[pl * NPIX + i0 + il] - mu) * rsg;
  }
  __syncthreads();
  for (int r = 0; r < 4; r++) {
    int i = i0 + cl + r * 8;
    hnT[((long)b * NPIX + i) * CCH + c0 + il] = f2bf(tile[il][cl + r * 8]);
  }
}

// ---------------- generic bf16 gemm_bt: C[m][n] = A[m][k] * B[n][k] ----------------
// m97 structure: 128x128 tile, BK=64, global_load_lds dwordx4 staging,
// 4 waves (2x2), 4x4 16x16x32 mfma frags per wave.
// OUTF32: 1 -> float C (scalar stores). 0 -> bf16 C via LDS-staged vector stores.
// BIASM: 0 none, 1 bias[m], 2 bias[n].
// EXPSUM: epilogue v=exp(v), atomicAdd row sums into lsum[z*NPIX+m].
// ROWSCALE: epilogue v *= 1/lsum[z*NPIX+m].
template <int OUTF32, int BIASM, bool RESID, bool SCALE, bool EXPSUM, bool ROWSCALE>
__global__ __launch_bounds__(256) void gemm_bt_k(
    const unsigned short* __restrict__ A, const unsigned short* __restrict__ B,
    void* __restrict__ Cv, const float* __restrict__ bias,
    const float* __restrict__ resid, float* __restrict__ lsum,
    int K, int lda, int ldb, int ldc,
    long sA, long sB, long sC, float scale) {
  int z = blockIdx.z;
  A += z * sA;
  B += z * sB;
  const int n0 = blockIdx.x * 128, m0 = blockIdx.y * 128;
  const int t = threadIdx.x;
  const int lane = t & 63, w = t >> 6;
  const int wr = w >> 1, wc = w & 1;

  // 33 KB: staging As[128][64] | Bs[128][64]; reused as C-tile [128][132] bf16
  __shared__ __align__(16) unsigned short LDSbuf[128 * 132];
  unsigned short* As = LDSbuf;
  unsigned short* Bs = LDSbuf + 128 * 64;

  f32x4 acc[4][4] = {};

  const int srow = t >> 3;       // 0..31
  const int scol = (t & 7) * 8;  // element offset within BK=64
  const unsigned short* ga = A + (long)(m0 + srow) * lda + scol;
  const unsigned short* gb = B + (long)(n0 + srow) * ldb + scol;
  char* lA = (char*)As + t * 16;
  char* lB = (char*)Bs + t * 16;
  const long stpa = (long)32 * lda;
  const long stpb = (long)32 * ldb;

  const int fr = lane & 15, fk = (lane >> 4) * 8;
  const unsigned short* rA = As + (wr * 64 + fr) * 64 + fk;
  const unsigned short* rB = Bs + (wc * 64 + fr) * 64 + fk;

  const int nkt = K >> 6;
  for (int kt = 0; kt < nkt; kt++) {
    const unsigned short* gak = ga + (long)kt * 64;
    const unsigned short* gbk = gb + (long)kt * 64;
    GLD16(gak, lA);
    GLD16(gak + stpa, lA + 4096);
    GLD16(gak + 2 * stpa, lA + 8192);
    GLD16(gak + 3 * stpa, lA + 12288);
    GLD16(gbk, lB);
    GLD16(gbk + stpb, lB + 4096);
    GLD16(gbk + 2 * stpb, lB + 8192);
    GLD16(gbk + 3 * stpb, lB + 12288);
    __syncthreads();
    for (int kk = 0; kk < 2; kk++) {
      bf16x8 af[4], bfr[4];
      for (int i = 0; i < 4; i++) af[i] = *(const bf16x8*)(rA + i * 16 * 64 + kk * 32);
      for (int i = 0; i < 4; i++) bfr[i] = *(const bf16x8*)(rB + i * 16 * 64 + kk * 32);
      for (int i = 0; i < 4; i++)
        for (int j = 0; j < 4; j++)
          acc[i][j] = __builtin_amdgcn_mfma_f32_16x16x32_bf16(af[i], bfr[j], acc[i][j], 0, 0, 0);
    }
    __syncthreads();
  }

  // epilogue: C/D layout col = lane&15, row = (lane>>4)*4 + r  (m89-verified)
  const int fq = lane >> 4;
  if (OUTF32) {
    float* Cf = (float*)Cv;
    for (int i = 0; i < 4; i++) {
      int mg = m0 + wr * 64 + i * 16 + fq * 4;
      for (int j = 0; j < 4; j++) {
        int ng = n0 + wc * 64 + j * 16 + fr;
        for (int r = 0; r < 4; r++) {
          float v = acc[i][j][r];
          if (SCALE) v *= scale;
          int m = mg + r;
          if (BIASM == 1) v += bias[m];
          else if (BIASM == 2) v += bias[ng];
          long off = z * sC + (long)m * ldc + ng;
          if (RESID) v += resid[off];
          Cf[off] = v;
        }
      }
    }
  } else {
    float linv[4][4];
    if (ROWSCALE) {
      for (int i = 0; i < 4; i++)
        for (int r = 0; r < 4; r++)
          linv[i][r] = 1.f / lsum[z * NPIX + m0 + wr * 64 + i * 16 + fq * 4 + r];
    }
    float rsum[4][4];
    if (EXPSUM) {
      for (int i = 0; i < 4; i++)
        for (int r = 0; r < 4; r++) rsum[i][r] = 0.f;
    }
    for (int i = 0; i < 4; i++) {
      int mrow = wr * 64 + i * 16 + fq * 4;
      for (int j = 0; j < 4; j++) {
        int ncol = wc * 64 + j * 16 + fr;
        for (int r = 0; r < 4; r++) {
          float v = acc[i][j][r];
          if (SCALE) v *= scale;
          if (BIASM == 1) v += bias[m0 + mrow + r];
          else if (BIASM == 2) v += bias[n0 + ncol];
          if (EXPSUM) { v = __expf(v); rsum[i][r] += v; }
          if (ROWSCALE) v *= linv[i][r];
          LDSbuf[(mrow + r) * 132 + ncol] = f2bf(v);
        }
      }
    }
    if (EXPSUM) {
      for (int i = 0; i < 4; i++)
        for (int r = 0; r < 4; r++) {
          float s = rsum[i][r];
          s += __shfl_xor(s, 1);
          s += __shfl_xor(s, 2);
          s += __shfl_xor(s, 4);
          s += __shfl_xor(s, 8);
          if (fr == 0)
            atomicAdd(&lsum[z * NPIX + m0 + wr * 64 + i * 16 + fq * 4 + r], s);
        }
    }
    __syncthreads();
    // vectorized copy-out: 4 passes, wave covers full 128B lines
    unsigned short* Cb = (unsigned short*)Cv;
    const int crow = t >> 3, ccol = (t & 7) * 16;
    for (int p = 0; p < 4; p++) {
      int row = p * 32 + crow;
      const unsigned short* src = LDSbuf + row * 132 + ccol;
      u16x8 c0 = *(const u16x8*)(src);
      u16x8 c1 = *(const u16x8*)(src + 8);
      unsigned short* dst = Cb + z * sC + (long)(m0 + row) * ldc + n0 + ccol;
      *(u16x8*)(dst) = c0;
      *(u16x8*)(dst + 8) = c1;
    }
  }
}

extern "C" void kernel_launch(void* const* d_in, const int* in_sizes, int n_in,
                              void* d_out, int out_size, void* d_ws, size_t ws_size,
                              hipStream_t stream) {
  const float* x  = (const float*)d_in[0];
  const float* wq = (const float*)d_in[1];
  const float* bq = (const float*)d_in[2];
  const float* wk = (const float*)d_in[3];
  const float* bk = (const float*)d_in[4];
  const float* wv = (const float*)d_in[5];
  const float* bv = (const float*)d_in[6];
  const float* wp = (const float*)d_in[7];
  const float* bp = (const float*)d_in[8];

  char* ws = (char*)d_ws;
  const long SLAB = (long)NPIX * CCH;     // 2M elems: one batch of hnT/V/Ot
  const long SLAB2 = (long)NPIX * 1024;   // 4M elems: one batch of QKt
  const long SLABP = (long)NPIX * NPIX;   // 16.8M elems: one batch of E

  float* stats = (float*)ws;                                  // 16 KB
  float* bqk = (float*)(ws + (32l << 10));                    // 4 KB
  float* lsum = (float*)(ws + (64l << 10));                   // 64 KB [b][i]
  unsigned short* wbf = (unsigned short*)(ws + (192l << 10)); // 2 MB
  unsigned short* hnT = (unsigned short*)(ws + (192l << 10) + (1l << 21));
  unsigned short* QKt = hnT + 4 * SLAB;   // [b][i][0:512 Q | 512:1024 K], 32 MB
  unsigned short* V   = QKt + 4 * SLAB2;  // [b][o][j], 16 MB
  unsigned short* Ot  = V + 4 * SLAB;     // [b][i][c], 16 MB
  unsigned short* S4  = Ot + 4 * SLAB;    // [b][i][j] bf16 E=exp(S), 128 MB
  // total: ~210 MB

  unsigned short* wv_bf = wbf + 2 * 262144;
  unsigned short* wp_bf = wbf + 3 * 262144;

  cast_weights_k<<<dim3(1024, 4, 1), 256, 0, stream>>>(wq, wk, wv, wp, wbf);
  bias_concat_k<<<dim3(4, 1, 1), 256, 0, stream>>>(bq, bk, bqk);
  zero_l_k<<<dim3(16, 1, 1), 256, 0, stream>>>(lsum);
  stats_k<<<dim3(NB * CCH, 1, 1), 256, 0, stream>>>(x, stats);
  norm_t_k<<<dim3(128, 16, 4), 256, 0, stream>>>(x, stats, hnT);

  // QKt[b][i][n] = hnT[b] . [wq;wk]^T + bqk   (n in 0..1023)
  gemm_bt_k<0, 2, false, false, false, false><<<dim3(8, 32, 4), 256, 0, stream>>>(
      hnT, wbf, QKt, bqk, nullptr, nullptr, 512, 512, 512, 1024, SLAB, 0, SLAB2, 1.f);
  // V[b][o][j] = Wv . hnT[b]^T + bv (bias over rows)
  gemm_bt_k<0, 1, false, false, false, false><<<dim3(32, 4, 4), 256, 0, stream>>>(
      wv_bf, hnT, V, bv, nullptr, nullptr, 512, 512, 512, 4096, 0, SLAB, SLAB, 1.f);

  const float isc = 0.044194173824159216f;  // 1/sqrt(512)
  // E[b][i][j] = exp(Q[b].K[b]^T / sqrt(C)) bf16; lsum[b][i] = sum_j E
  gemm_bt_k<0, 0, false, true, true, false><<<dim3(32, 32, 4), 256, 0, stream>>>(
      QKt, QKt + 512, S4, nullptr, nullptr, lsum, 512, 1024, 1024, 4096,
      SLAB2, SLAB2, SLABP, isc);
  // Ot[b][i][c] = (E[b] . V[b]^T) / lsum[b][i]
  gemm_bt_k<0, 0, false, false, false, true><<<dim3(4, 32, 4), 256, 0, stream>>>(
      S4, V, Ot, nullptr, nullptr, lsum, 4096, 4096, 4096, 512, SLABP, SLAB, SLAB, 1.f);
  // out[b][o][i] = x + Wp . Ot[b]^T + bp
  gemm_bt_k<1, 1, true, false, false, false><<<dim3(32, 4, 4), 256, 0, stream>>>(
      wp_bf, Ot, d_out, bp, x, nullptr, 512, 512, 512, 4096, 0, SLAB, SLAB, 1.f);
}

// Round 6
// 315.428 us; speedup vs baseline: 1.1769x; 1.1769x over previous
//
#include <hip/hip_runtime.h>
#include <hip/hip_bf16.h>

typedef short bf16x8 __attribute__((ext_vector_type(8)));
typedef float f32x4 __attribute__((ext_vector_type(4)));

#define CCH 512
#define NPIX 4096
#define NB 4

__device__ inline unsigned short f2bf(float f) {
  union { __hip_bfloat16 h; unsigned short u; } cv;
  cv.h = __float2bfloat16(f);
  return cv.u;
}

#define GLD16(gp, lp) __builtin_amdgcn_global_load_lds( \
    (const __attribute__((address_space(1))) unsigned int*)(gp), \
    (__attribute__((address_space(3))) unsigned int*)(lp), 16, 0, 0)

// ---------------- weight fp32 -> bf16 cast ----------------
__global__ __launch_bounds__(256) void cast_weights_k(
    const float* __restrict__ w0, const float* __restrict__ w1,
    const float* __restrict__ w2, const float* __restrict__ w3,
    unsigned short* __restrict__ out) {
  int z = blockIdx.y;
  const float* src = (z == 0) ? w0 : (z == 1) ? w1 : (z == 2) ? w2 : w3;
  long i = (long)blockIdx.x * 256 + threadIdx.x;
  out[(long)z * CCH * CCH + i] = f2bf(src[i]);
}

// ---------------- concat bq,bk -> bqk[1024] ----------------
__global__ __launch_bounds__(256) void bias_concat_k(
    const float* __restrict__ bq, const float* __restrict__ bk,
    float* __restrict__ bqk) {
  int i = blockIdx.x * 256 + threadIdx.x;
  bqk[i] = (i < CCH) ? bq[i] : bk[i - CCH];
}

// ---------------- zero the softmax row-sum accumulator ----------------
__global__ __launch_bounds__(256) void zero_l_k(float* __restrict__ lsum) {
  int i = (blockIdx.x * 256 + threadIdx.x) * 4;
  *(float4*)(lsum + i) = make_float4(0.f, 0.f, 0.f, 0.f);
}

// ---------------- instance-norm stats: one block per (b,c) plane ----------------
__global__ __launch_bounds__(256) void stats_k(const float* __restrict__ x,
                                               float* __restrict__ stats) {
  long plane = blockIdx.x;
  const float4* p = (const float4*)(x + plane * NPIX);
  int t = threadIdx.x;
  float s = 0.f, q = 0.f;
  for (int c = 0; c < 4; c++) {
    float4 v = p[c * 256 + t];
    s += v.x + v.y + v.z + v.w;
    q += v.x * v.x + v.y * v.y + v.z * v.z + v.w * v.w;
  }
  for (int off = 32; off; off >>= 1) { s += __shfl_xor(s, off); q += __shfl_xor(q, off); }
  __shared__ float rs[4], rq[4];
  int w = t >> 6;
  if ((t & 63) == 0) { rs[w] = s; rq[w] = q; }
  __syncthreads();
  if (t == 0) {
    s = rs[0] + rs[1] + rs[2] + rs[3];
    q = rq[0] + rq[1] + rq[2] + rq[3];
    float mu = s * (1.f / NPIX);
    float var = q * (1.f / NPIX) - mu * mu;
    stats[2 * plane] = mu;
    stats[2 * plane + 1] = rsqrtf(var + 1e-5f);
  }
}

// ---------------- normalize + transpose: x[b][c][i] -> hnT[b][i][c] bf16 ----------------
__global__ __launch_bounds__(256) void norm_t_k(const float* __restrict__ x,
                                                const float* __restrict__ stats,
                                                unsigned short* __restrict__ hnT) {
  int b = blockIdx.z;
  int c0 = blockIdx.y * 32, i0 = blockIdx.x * 32;
  __shared__ float tile[32][33];
  int t = threadIdx.x;
  int il = t & 31, cl = t >> 5;  // cl in 0..7
  for (int r = 0; r < 4; r++) {
    int c = c0 + cl + r * 8;
    long pl = (long)b * CCH + c;
    float mu = stats[2 * pl], rsg = stats[2 * pl + 1];
    tile[cl + r * 8][il] = (x[pl * NPIX + i0 + il] - mu) * rsg;
  }
  __syncthreads();
  for (int r = 0; r < 4; r++) {
    int i = i0 + cl + r * 8;
    hnT[((long)b * NPIX + i) * CCH + c0 + il] = f2bf(tile[il][cl + r * 8]);
  }
}

// ---------------- generic bf16 gemm_bt: C[m][n] = A[m][k] * B[n][k] ----------------
// m97 structure: 128x128 tile, BK=64, global_load_lds dwordx4 staging,
// 4 waves (2x2), 4x4 16x16x32 mfma frags per wave.
// LDS XOR chunk-swizzle (T2-style): logical element (row, e) lives at LDS elem
// addr row*64 + ((e>>3) ^ (row&7))*8 + (e&7). Staging pre-swizzles the GLOBAL
// source column (dest stays linear for global_load_lds); frag reads apply the
// same XOR. Involution on both sides (rule 21).
// OUTF32: 1 -> float C. BIASM: 0 none, 1 bias[m], 2 bias[n].
// EXPSUM: epilogue v=exp(v), atomicAdd row sums into lsum[z*NPIX+m].
// ROWSCALE: epilogue v *= 1/lsum[z*NPIX+m].
template <int OUTF32, int BIASM, bool RESID, bool SCALE, bool EXPSUM, bool ROWSCALE>
__global__ __launch_bounds__(256) void gemm_bt_k(
    const unsigned short* __restrict__ A, const unsigned short* __restrict__ B,
    void* __restrict__ Cv, const float* __restrict__ bias,
    const float* __restrict__ resid, float* __restrict__ lsum,
    int K, int lda, int ldb, int ldc,
    long sA, long sB, long sC, float scale) {
  int z = blockIdx.z;
  A += z * sA;
  B += z * sB;
  const int n0 = blockIdx.x * 128, m0 = blockIdx.y * 128;
  const int t = threadIdx.x;
  const int lane = t & 63, w = t >> 6;
  const int wr = w >> 1, wc = w & 1;

  __shared__ __align__(16) unsigned short As[128 * 64];  // 16 KB, [row][64] swizzled
  __shared__ __align__(16) unsigned short Bs[128 * 64];  // 16 KB

  f32x4 acc[4][4] = {};

  // staging: instr p covers rows p*32 + (t>>3); within-tile source chunk is
  // pre-swizzled: ch_src = (t&7) ^ (row&7), row&7 == (t>>3)&7 for all p.
  const int srow = t >> 3;                        // 0..31
  const int scol = (((t & 7) ^ (srow & 7)) * 8);  // swizzled source col
  const unsigned short* ga = A + (long)(m0 + srow) * lda + scol;
  const unsigned short* gb = B + (long)(n0 + srow) * ldb + scol;
  char* lA = (char*)As + t * 16;
  char* lB = (char*)Bs + t * 16;
  const long stpa = (long)32 * lda;
  const long stpb = (long)32 * ldb;

  const int fr = lane & 15, fq = lane >> 4;
  const int chx = fr & 7;  // read-side XOR key (row&7 == fr&7)
  const unsigned short* rA = As + (wr * 64 + fr) * 64;
  const unsigned short* rB = Bs + (wc * 64 + fr) * 64;

  const int nkt = K >> 6;
  for (int kt = 0; kt < nkt; kt++) {
    const unsigned short* gak = ga + (long)kt * 64;
    const unsigned short* gbk = gb + (long)kt * 64;
    GLD16(gak, lA);
    GLD16(gak + stpa, lA + 4096);
    GLD16(gak + 2 * stpa, lA + 8192);
    GLD16(gak + 3 * stpa, lA + 12288);
    GLD16(gbk, lB);
    GLD16(gbk + stpb, lB + 4096);
    GLD16(gbk + 2 * stpb, lB + 8192);
    GLD16(gbk + 3 * stpb, lB + 12288);
    __syncthreads();
    for (int kk = 0; kk < 2; kk++) {
      const int offA = ((fq + kk * 4) ^ chx) * 8;  // swizzled chunk offset
      bf16x8 af[4], bfr[4];
      for (int i = 0; i < 4; i++) af[i] = *(const bf16x8*)(rA + i * 1024 + offA);
      for (int i = 0; i < 4; i++) bfr[i] = *(const bf16x8*)(rB + i * 1024 + offA);
      for (int i = 0; i < 4; i++)
        for (int j = 0; j < 4; j++)
          acc[i][j] = __builtin_amdgcn_mfma_f32_16x16x32_bf16(af[i], bfr[j], acc[i][j], 0, 0, 0);
    }
    __syncthreads();
  }

  // epilogue: C/D layout col = lane&15, row = (lane>>4)*4 + r  (m89-verified)
  if (OUTF32) {
    float* Cf = (float*)Cv;
    for (int i = 0; i < 4; i++) {
      int mg = m0 + wr * 64 + i * 16 + fq * 4;
      for (int j = 0; j < 4; j++) {
        int ng = n0 + wc * 64 + j * 16 + fr;
        for (int r = 0; r < 4; r++) {
          float v = acc[i][j][r];
          if (SCALE) v *= scale;
          int m = mg + r;
          if (BIASM == 1) v += bias[m];
          else if (BIASM == 2) v += bias[ng];
          long off = z * sC + (long)m * ldc + ng;
          if (RESID) v += resid[off];
          Cf[off] = v;
        }
      }
    }
  } else {
    float linv[4][4];
    if (ROWSCALE) {
      for (int i = 0; i < 4; i++)
        for (int r = 0; r < 4; r++)
          linv[i][r] = 1.f / lsum[z * NPIX + m0 + wr * 64 + i * 16 + fq * 4 + r];
    }
    float rsum[4][4];
    if (EXPSUM) {
      for (int i = 0; i < 4; i++)
        for (int r = 0; r < 4; r++) rsum[i][r] = 0.f;
    }
    unsigned short* Cb = (unsigned short*)Cv;
    for (int i = 0; i < 4; i++) {
      int mg = m0 + wr * 64 + i * 16 + fq * 4;
      for (int j = 0; j < 4; j++) {
        int ng = n0 + wc * 64 + j * 16 + fr;
        for (int r = 0; r < 4; r++) {
          float v = acc[i][j][r];
          if (SCALE) v *= scale;
          if (BIASM == 1) v += bias[mg + r];
          else if (BIASM == 2) v += bias[ng];
          if (EXPSUM) { v = __expf(v); rsum[i][r] += v; }
          if (ROWSCALE) v *= linv[i][r];
          Cb[z * sC + (long)(mg + r) * ldc + ng] = f2bf(v);
        }
      }
    }
    if (EXPSUM) {
      for (int i = 0; i < 4; i++)
        for (int r = 0; r < 4; r++) {
          float s = rsum[i][r];
          s += __shfl_xor(s, 1);
          s += __shfl_xor(s, 2);
          s += __shfl_xor(s, 4);
          s += __shfl_xor(s, 8);
          if (fr == 0)
            atomicAdd(&lsum[z * NPIX + m0 + wr * 64 + i * 16 + fq * 4 + r], s);
        }
    }
  }
}

extern "C" void kernel_launch(void* const* d_in, const int* in_sizes, int n_in,
                              void* d_out, int out_size, void* d_ws, size_t ws_size,
                              hipStream_t stream) {
  const float* x  = (const float*)d_in[0];
  const float* wq = (const float*)d_in[1];
  const float* bq = (const float*)d_in[2];
  const float* wk = (const float*)d_in[3];
  const float* bk = (const float*)d_in[4];
  const float* wv = (const float*)d_in[5];
  const float* bv = (const float*)d_in[6];
  const float* wp = (const float*)d_in[7];
  const float* bp = (const float*)d_in[8];

  char* ws = (char*)d_ws;
  const long SLAB = (long)NPIX * CCH;     // 2M elems: one batch of hnT/V/Ot
  const long SLAB2 = (long)NPIX * 1024;   // 4M elems: one batch of QKt
  const long SLABP = (long)NPIX * NPIX;   // 16.8M elems: one batch of E

  float* stats = (float*)ws;                                  // 16 KB
  float* bqk = (float*)(ws + (32l << 10));                    // 4 KB
  float* lsum = (float*)(ws + (64l << 10));                   // 64 KB [b][i]
  unsigned short* wbf = (unsigned short*)(ws + (192l << 10)); // 2 MB
  unsigned short* hnT = (unsigned short*)(ws + (192l << 10) + (1l << 21));
  unsigned short* QKt = hnT + 4 * SLAB;   // [b][i][0:512 Q | 512:1024 K], 32 MB
  unsigned short* V   = QKt + 4 * SLAB2;  // [b][o][j], 16 MB
  unsigned short* Ot  = V + 4 * SLAB;     // [b][i][c], 16 MB
  unsigned short* S4  = Ot + 4 * SLAB;    // [b][i][j] bf16 E=exp(S), 128 MB
  // total: ~210 MB

  unsigned short* wv_bf = wbf + 2 * 262144;
  unsigned short* wp_bf = wbf + 3 * 262144;

  cast_weights_k<<<dim3(1024, 4, 1), 256, 0, stream>>>(wq, wk, wv, wp, wbf);
  bias_concat_k<<<dim3(4, 1, 1), 256, 0, stream>>>(bq, bk, bqk);
  zero_l_k<<<dim3(16, 1, 1), 256, 0, stream>>>(lsum);
  stats_k<<<dim3(NB * CCH, 1, 1), 256, 0, stream>>>(x, stats);
  norm_t_k<<<dim3(128, 16, 4), 256, 0, stream>>>(x, stats, hnT);

  // QKt[b][i][n] = hnT[b] . [wq;wk]^T + bqk   (n in 0..1023)
  gemm_bt_k<0, 2, false, false, false, false><<<dim3(8, 32, 4), 256, 0, stream>>>(
      hnT, wbf, QKt, bqk, nullptr, nullptr, 512, 512, 512, 1024, SLAB, 0, SLAB2, 1.f);
  // V[b][o][j] = Wv . hnT[b]^T + bv (bias over rows)
  gemm_bt_k<0, 1, false, false, false, false><<<dim3(32, 4, 4), 256, 0, stream>>>(
      wv_bf, hnT, V, bv, nullptr, nullptr, 512, 512, 512, 4096, 0, SLAB, SLAB, 1.f);

  const float isc = 0.044194173824159216f;  // 1/sqrt(512)
  // E[b][i][j] = exp(Q[b].K[b]^T / sqrt(C)) bf16; lsum[b][i] = sum_j E
  gemm_bt_k<0, 0, false, true, true, false><<<dim3(32, 32, 4), 256, 0, stream>>>(
      QKt, QKt + 512, S4, nullptr, nullptr, lsum, 512, 1024, 1024, 4096,
      SLAB2, SLAB2, SLABP, isc);
  // Ot[b][i][c] = (E[b] . V[b]^T) / lsum[b][i]
  gemm_bt_k<0, 0, false, false, false, true><<<dim3(4, 32, 4), 256, 0, stream>>>(
      S4, V, Ot, nullptr, nullptr, lsum, 4096, 4096, 4096, 512, SLABP, SLAB, SLAB, 1.f);
  // out[b][o][i] = x + Wp . Ot[b]^T + bp
  gemm_bt_k<1, 1, true, false, false, false><<<dim3(32, 4, 4), 256, 0, stream>>>(
      wp_bf, Ot, d_out, bp, x, nullptr, 512, 512, 512, 4096, 0, SLAB, SLAB, 1.f);
}